// Round 5
// baseline (1035.900 us; speedup 1.0000x reference)
//
#include <hip/hip_runtime.h>
#include <hip/hip_bf16.h>

// Problem constants
constexpr int Bn   = 128;    // batch
constexpr int In   = 800;    // genes per case
constexpr int En   = 512;    // embed dim
constexpr int V1   = 19001;  // vocab + padding row
constexpr int NHn  = 8;      // heads
constexpr int NBn  = 4;      // attention blocks
constexpr int OUTn = 5000;   // output genes

constexpr int NVP  = 19008;  // V1 padded to 32*594
constexpr int NBIN = 2 * NVP;  // bins keyed (b>>6)*NVP + v

// d_out layout (floats): preds [B,OUT] | attns [NB,B,I] | hiddens [NB,B,E]
constexpr int OFF_ATTN = Bn * OUTn;                 // 640000
constexpr int OFF_HID  = OFF_ATTN + NBn * Bn * In;  // 1049600

typedef __attribute__((ext_vector_type(8))) short bf16x8;
typedef __attribute__((ext_vector_type(8))) unsigned short u16x8;
typedef __attribute__((ext_vector_type(4))) float f32x4;

__device__ inline ushort f2bf(float x) {
    __hip_bfloat16 h = __float2bfloat16(x);
    return *reinterpret_cast<ushort*>(&h);
}
__device__ inline float bf2f(ushort u) {
    return __uint_as_float(((unsigned)u) << 16);
}
__device__ inline bf16x8 asbf(u16x8 u) {
    union { u16x8 u; bf16x8 b; } x; x.u = u; return x.b;
}

// ---------------------------------------------------------------------------
// K0: Wkt[nb][n][k] = bf16(Wk[nb][k][n]) via LDS tile transpose (coalesced IO)
// ---------------------------------------------------------------------------
__global__ __launch_bounds__(256)
void k_prep(const float* __restrict__ Wk, ushort* __restrict__ Wkt) {
    __shared__ float ts[64][65];
    const int n0 = blockIdx.x * 64, k0 = blockIdx.y * 64, nb = blockIdx.z;
    const int t = threadIdx.x;
    {
        const int kr = t >> 2, nc = (t & 3) * 16;
        const float* p = Wk + (((size_t)nb * En) + (k0 + kr)) * En + n0 + nc;
#pragma unroll
        for (int j = 0; j < 4; ++j) {
            const float4 v = *(const float4*)(p + j * 4);
            ts[kr][nc + j * 4 + 0] = v.x; ts[kr][nc + j * 4 + 1] = v.y;
            ts[kr][nc + j * 4 + 2] = v.z; ts[kr][nc + j * 4 + 3] = v.w;
        }
    }
    __syncthreads();
    {
        const int nr = t >> 2, kc = (t & 3) * 16;
        ushort* d = Wkt + (((size_t)nb * En) + (n0 + nr)) * En + k0 + kc;
        ushort4 o;
#pragma unroll
        for (int j = 0; j < 4; ++j) {
            o.x = f2bf(ts[kc + j * 4 + 0][nr]); o.y = f2bf(ts[kc + j * 4 + 1][nr]);
            o.z = f2bf(ts[kc + j * 4 + 2][nr]); o.w = f2bf(ts[kc + j * 4 + 3][nr]);
            *(ushort4*)(d + j * 4) = o;
        }
    }
}

// ---------------------------------------------------------------------------
__global__ __launch_bounds__(256)
void k_zero(float* __restrict__ p, int n) {
    const int i = blockIdx.x * 256 + threadIdx.x;
    if (i < n) p[i] = 0.f;
}

// ---------------------------------------------------------------------------
// Inverted index over sga: bin = (b>>6)*NVP + v
// ---------------------------------------------------------------------------
__global__ __launch_bounds__(256)
void k_hist(const int* __restrict__ sga, int* __restrict__ cnt) {
    const int idx = blockIdx.x * 256 + threadIdx.x;
    if (idx < Bn * In) {
        const int v = sga[idx];
        const int b = idx / In;
        atomicAdd(&cnt[(b >> 6) * NVP + v], 1);
    }
}

__global__ __launch_bounds__(256)
void k_scan(const int* __restrict__ cnt, int* __restrict__ offs,
            int* __restrict__ cursor) {
    __shared__ int tsum[256];
    const int t = threadIdx.x;
    const int CH = 149;  // 256*149 = 38144 >= NBIN
    const int base = t * CH;
    int s = 0;
    for (int j = 0; j < CH; ++j) {
        const int idx = base + j;
        if (idx < NBIN) s += cnt[idx];
    }
    tsum[t] = s;
    __syncthreads();
    // Hillis-Steele inclusive scan
    for (int off = 1; off < 256; off <<= 1) {
        const int v = (t >= off) ? tsum[t - off] : 0;
        __syncthreads();
        tsum[t] += v;
        __syncthreads();
    }
    int running = (t == 0) ? 0 : tsum[t - 1];
    for (int j = 0; j < CH; ++j) {
        const int idx = base + j;
        if (idx < NBIN) {
            const int cv = cnt[idx];
            offs[idx] = running;
            cursor[idx] = running;
            running += cv;
        }
    }
    if (t == 255) offs[NBIN] = running;
}

__global__ __launch_bounds__(256)
void k_fill(const int* __restrict__ sga, int* __restrict__ cursor,
            int2* __restrict__ payload) {
    const int idx = blockIdx.x * 256 + threadIdx.x;
    if (idx < Bn * In) {
        const int v = sga[idx];
        const int b = idx / In;
        const int i = idx - b * In;
        const int pos = atomicAdd(&cursor[(b >> 6) * NVP + v], 1);
        payload[pos] = make_int2(v, (b << 10) | i);
    }
}

// ---------------------------------------------------------------------------
// K1: scoresv[nb][v][h] from keys = tanh(T@Wk+bk), scores = keys@Wq.
// No LDS in main loop: MFMA fragments loaded directly global->VGPR.
// Block = 32 rows x 512 cols; 4 waves each 32x128 (acc[2][8]).
// B frags from L2-resident Wkt[n][k]; A frags from T fp32 (+cvt), wave 0
// side-stores bf16 rows to Tbf. Epilogue: tanh + VALU head-dots + butterfly
// + tiny LDS cross-wave reduce -> direct scoresv stores (bq cancels).
// ---------------------------------------------------------------------------
template <bool TBF>
__global__ __launch_bounds__(256, 3)
void k_scores(const float* __restrict__ T, const ushort* __restrict__ Wkt,
              const float* __restrict__ bk, const float* __restrict__ Wq,
              float* __restrict__ scoresv, ushort* __restrict__ Tbf) {
    __shared__ float red[4][32][NHn];  // 4 KB
    const int v0 = blockIdx.x * 32, nb = blockIdx.y;
    const int tid = threadIdx.x, lane = tid & 63, wv = tid >> 6;
    const int q = lane >> 4, c = lane & 15;

    const float*  Tb = T + (size_t)nb * V1 * En;
    const ushort* Wn = Wkt + (size_t)nb * En * En;

    const int vr0 = v0 + c, vr1 = v0 + 16 + c;
    const bool ok0 = vr0 < V1, ok1 = vr1 < V1;
    const float* a0p = Tb + (size_t)vr0 * En + q * 8;
    const float* a1p = Tb + (size_t)vr1 * En + q * 8;
    ushort* t0p = Tbf + ((size_t)nb * V1 + vr0) * En + q * 8;
    ushort* t1p = Tbf + ((size_t)nb * V1 + vr1) * En + q * 8;

    const ushort* bp[8];
#pragma unroll
    for (int nt = 0; nt < 8; ++nt)
        bp[nt] = Wn + (size_t)(wv * 128 + nt * 16 + c) * En + q * 8;

    f32x4 acc[2][8];
#pragma unroll
    for (int mt = 0; mt < 2; ++mt)
#pragma unroll
        for (int nt = 0; nt < 8; ++nt) acc[mt][nt] = (f32x4)0.0f;

#pragma unroll 2
    for (int it = 0; it < 16; ++it) {
        const int k0 = it * 32;
        u16x8 u0, u1;
        {
            float4 f0 = make_float4(0, 0, 0, 0), f1 = f0, g0 = f0, g1 = f0;
            if (ok0) { f0 = *(const float4*)(a0p + k0); f1 = *(const float4*)(a0p + k0 + 4); }
            if (ok1) { g0 = *(const float4*)(a1p + k0); g1 = *(const float4*)(a1p + k0 + 4); }
            u0[0] = f2bf(f0.x); u0[1] = f2bf(f0.y); u0[2] = f2bf(f0.z); u0[3] = f2bf(f0.w);
            u0[4] = f2bf(f1.x); u0[5] = f2bf(f1.y); u0[6] = f2bf(f1.z); u0[7] = f2bf(f1.w);
            u1[0] = f2bf(g0.x); u1[1] = f2bf(g0.y); u1[2] = f2bf(g0.z); u1[3] = f2bf(g0.w);
            u1[4] = f2bf(g1.x); u1[5] = f2bf(g1.y); u1[6] = f2bf(g1.z); u1[7] = f2bf(g1.w);
        }
        if (TBF && wv == 0) {
            if (ok0) *(u16x8*)(t0p + k0) = u0;
            if (ok1) *(u16x8*)(t1p + k0) = u1;
        }
        const bf16x8 a0 = asbf(u0), a1 = asbf(u1);
#pragma unroll
        for (int nt = 0; nt < 8; ++nt) {
            const bf16x8 bF = *(const bf16x8*)(bp[nt] + k0);
            acc[0][nt] = __builtin_amdgcn_mfma_f32_16x16x32_bf16(a0, bF, acc[0][nt], 0, 0, 0);
            acc[1][nt] = __builtin_amdgcn_mfma_f32_16x16x32_bf16(a1, bF, acc[1][nt], 0, 0, 0);
        }
    }

    // keys = tanh(acc + bk[col])
#pragma unroll
    for (int nt = 0; nt < 8; ++nt) {
        const float bb = bk[nb * En + wv * 128 + nt * 16 + c];
#pragma unroll
        for (int mt = 0; mt < 2; ++mt)
#pragma unroll
            for (int r = 0; r < 4; ++r)
                acc[mt][nt][r] = tanhf(acc[mt][nt][r] + bb);
    }

    // per-head dots over this wave's 128 cols + 16-lane butterfly
    for (int h = 0; h < NHn; ++h) {
        float wqh[8];
#pragma unroll
        for (int nt = 0; nt < 8; ++nt)
            wqh[nt] = Wq[((size_t)nb * En + wv * 128 + nt * 16 + c) * NHn + h];
        float p0[4], p1[4];
#pragma unroll
        for (int r = 0; r < 4; ++r) {
            float s0 = 0.f, s1 = 0.f;
#pragma unroll
            for (int nt = 0; nt < 8; ++nt) {
                s0 += acc[0][nt][r] * wqh[nt];
                s1 += acc[1][nt][r] * wqh[nt];
            }
            p0[r] = s0; p1[r] = s1;
        }
#pragma unroll
        for (int m = 1; m < 16; m <<= 1) {
#pragma unroll
            for (int r = 0; r < 4; ++r) {
                p0[r] += __shfl_xor(p0[r], m, 64);
                p1[r] += __shfl_xor(p1[r], m, 64);
            }
        }
        if (c == h) {
#pragma unroll
            for (int r = 0; r < 4; ++r) {
                red[wv][q * 4 + r][h]      = p0[r];
                red[wv][16 + q * 4 + r][h] = p1[r];
            }
        }
    }
    __syncthreads();
    if (tid < 32 * NHn) {
        const int row = tid >> 3, h = tid & 7;
        const int vr = v0 + row;
        if (vr < V1)
            scoresv[((size_t)nb * V1 + vr) * NHn + h] =
                red[0][row][h] + red[1][row][h] + red[2][row][h] + red[3][row][h];
    }
}

// ---------------------------------------------------------------------------
// K2: masked softmax over genes, per (nb, b); writes attn weights (head-sum).
// ---------------------------------------------------------------------------
__global__ __launch_bounds__(256)
void k_softmax(const int* __restrict__ sga, const float* __restrict__ scoresv,
               float* __restrict__ attn_out) {
    const int b  = blockIdx.x;
    const int nb = blockIdx.y;
    const int tid = threadIdx.x;
    const int lane = tid & 63;
    const int wid  = tid >> 6;
    __shared__ float red[4 * NHn];

    float sc[4][NHn];
    int ivals[4];
#pragma unroll
    for (int s = 0; s < 4; ++s) {
        const int i = tid + s * 256;
        ivals[s] = i;
        if (i < In) {
            const int v = sga[b * In + i];
            const float4 s0 = *(const float4*)(scoresv + ((size_t)nb * V1 + v) * NHn);
            const float4 s1 = *(const float4*)(scoresv + ((size_t)nb * V1 + v) * NHn + 4);
            sc[s][0] = s0.x; sc[s][1] = s0.y; sc[s][2] = s0.z; sc[s][3] = s0.w;
            sc[s][4] = s1.x; sc[s][5] = s1.y; sc[s][6] = s1.z; sc[s][7] = s1.w;
            if (v == 0) {
#pragma unroll
                for (int n = 0; n < NHn; ++n) sc[s][n] = -1e9f;
            }
        } else {
#pragma unroll
            for (int n = 0; n < NHn; ++n) sc[s][n] = -3.0e38f;
        }
    }

    float lm[NHn];
#pragma unroll
    for (int n = 0; n < NHn; ++n)
        lm[n] = fmaxf(fmaxf(sc[0][n], sc[1][n]), fmaxf(sc[2][n], sc[3][n]));
#pragma unroll
    for (int m = 1; m < 64; m <<= 1) {
#pragma unroll
        for (int n = 0; n < NHn; ++n) lm[n] = fmaxf(lm[n], __shfl_xor(lm[n], m, 64));
    }
    if (lane == 0) {
#pragma unroll
        for (int n = 0; n < NHn; ++n) red[wid * NHn + n] = lm[n];
    }
    __syncthreads();
    float M[NHn];
#pragma unroll
    for (int n = 0; n < NHn; ++n)
        M[n] = fmaxf(fmaxf(red[n], red[NHn + n]), fmaxf(red[2 * NHn + n], red[3 * NHn + n]));
    __syncthreads();

    float ls[NHn];
#pragma unroll
    for (int n = 0; n < NHn; ++n) ls[n] = 0.f;
#pragma unroll
    for (int s = 0; s < 4; ++s) {
#pragma unroll
        for (int n = 0; n < NHn; ++n) {
            sc[s][n] = expf(sc[s][n] - M[n]);
            ls[n] += sc[s][n];
        }
    }
#pragma unroll
    for (int m = 1; m < 64; m <<= 1) {
#pragma unroll
        for (int n = 0; n < NHn; ++n) ls[n] += __shfl_xor(ls[n], m, 64);
    }
    if (lane == 0) {
#pragma unroll
        for (int n = 0; n < NHn; ++n) red[wid * NHn + n] = ls[n];
    }
    __syncthreads();
    float inv[NHn];
#pragma unroll
    for (int n = 0; n < NHn; ++n) {
        const float S = red[n] + red[NHn + n] + red[2 * NHn + n] + red[3 * NHn + n];
        inv[n] = 1.0f / S;
    }

#pragma unroll
    for (int s = 0; s < 4; ++s) {
        if (ivals[s] < In) {
            float w = 0.f;
#pragma unroll
            for (int n = 0; n < NHn; ++n) w += sc[s][n] * inv[n];
            attn_out[((size_t)nb * Bn + b) * In + ivals[s]] = w;
        }
    }
}

// ---------------------------------------------------------------------------
// K3 (fast path): inverted-index weighted accumulation.
// Grid (32 v-segs, eh|bh<<1, nb). Block: LDS acc[64][256] (64 KB).
// Wave wv processes entries with (b & 3) == wv (race-free LDS RMW).
// Flush via atomicAdd into pre-zeroed embw.
// ---------------------------------------------------------------------------
__global__ __launch_bounds__(256)
void k_emb2(const int2* __restrict__ payload, const int* __restrict__ offs,
            const float* __restrict__ attn, const ushort* __restrict__ Tbf,
            float* __restrict__ embw) {
    __shared__ float acc[64][256];  // 64 KB
    const int seg = blockIdx.x;
    const int eh  = blockIdx.y & 1;
    const int bh  = blockIdx.y >> 1;
    const int nb  = blockIdx.z;
    const int tid = threadIdx.x, lane = tid & 63, wv = tid >> 6;

    float* af = &acc[0][0];
    for (int i = tid; i < 64 * 256; i += 256) af[i] = 0.f;
    __syncthreads();

    const int binlo = bh * NVP + seg * 594;
    const int e0 = offs[binlo], e1 = offs[binlo + 594];
    const ushort* Tb = Tbf + (size_t)nb * V1 * En + eh * 256;
    const float* at = attn + (size_t)nb * Bn * In;

    for (int e = e0; e < e1; ++e) {
        const int2 pv = payload[e];
        const int b = pv.y >> 10;
        if ((b & 3) != wv) continue;
        const int i = pv.y & 1023;
        const float w = at[b * In + i];
        const ushort4 tv = *(const ushort4*)(Tb + (size_t)pv.x * En + lane * 4);
        float4* ap = (float4*)&acc[b & 63][lane * 4];
        float4 a = *ap;
        a.x += w * bf2f(tv.x);
        a.y += w * bf2f(tv.y);
        a.z += w * bf2f(tv.z);
        a.w += w * bf2f(tv.w);
        *ap = a;
    }
    __syncthreads();

    // flush: col = tid, rows 0..63
    float* dst = embw + ((size_t)nb * Bn + bh * 64) * En + eh * 256 + tid;
#pragma unroll 4
    for (int bl = 0; bl < 64; ++bl)
        atomicAdd(dst + (size_t)bl * En, acc[bl][tid]);
}

// ---------------------------------------------------------------------------
// K3 (fallback): direct fp32 gather (used when ws too small for Tbf/index)
// ---------------------------------------------------------------------------
__global__ __launch_bounds__(512)
void k_embf(const int* __restrict__ sga, const float* __restrict__ attn,
            const float* __restrict__ T, float* __restrict__ emb) {
    const int b  = blockIdx.x;
    const int nb = blockIdx.y;
    __shared__ int   sv[In];
    __shared__ float sw[In];
    __shared__ float pa[8][En];
    for (int idx = threadIdx.x; idx < In; idx += 512) {
        sv[idx] = sga[b * In + idx];
        sw[idx] = attn[((size_t)nb * Bn + b) * In + idx];
    }
    __syncthreads();
    const int wave = threadIdx.x >> 6, lane = threadIdx.x & 63;
    float a[8];
#pragma unroll
    for (int j = 0; j < 8; ++j) a[j] = 0.f;
    const float* Tb = T + (size_t)nb * V1 * En;
#pragma unroll 4
    for (int g = 0; g < 100; ++g) {
        const int i = wave * 100 + g;
        const int v = sv[i];
        const float w = sw[i];
        const float4* p = (const float4*)(Tb + (size_t)v * En) + lane * 2;
        const float4 t0 = p[0], t1 = p[1];
        a[0] += w * t0.x; a[1] += w * t0.y; a[2] += w * t0.z; a[3] += w * t0.w;
        a[4] += w * t1.x; a[5] += w * t1.y; a[6] += w * t1.z; a[7] += w * t1.w;
    }
#pragma unroll
    for (int j = 0; j < 8; ++j) pa[wave][lane * 8 + j] = a[j];
    __syncthreads();
    const int t = threadIdx.x;
    float s = 0.f;
#pragma unroll
    for (int wv = 0; wv < 8; ++wv) s += pa[wv][t];
    emb[((size_t)nb * Bn + b) * En + t] = s;
}

// ---------------------------------------------------------------------------
// K4a: curr0 = relu(emb0 + can_emb[can]); hiddens[0] = curr0
// ---------------------------------------------------------------------------
__global__ __launch_bounds__(256)
void k_step0(const float* __restrict__ emb0, const int* __restrict__ can,
             const float* __restrict__ can_emb, float* __restrict__ cur,
             float* __restrict__ hid) {
    const int b = blockIdx.x;
    const int e0 = threadIdx.x * 2;
    const int c = can[b];
    float2 v = *(const float2*)(emb0 + (size_t)b * En + e0);
    const float2 ce = *(const float2*)(can_emb + (size_t)c * En + e0);
    v.x = fmaxf(v.x + ce.x, 0.f);
    v.y = fmaxf(v.y + ce.y, 0.f);
    *(float2*)(cur + (size_t)b * En + e0) = v;
    *(float2*)(hid + (size_t)b * En + e0) = v;
}

// ---------------------------------------------------------------------------
// K4b: curr = act(emb_i + prev @ Wh), K-split, grid (b, 4 col-chunks)
// ---------------------------------------------------------------------------
__global__ __launch_bounds__(256)
void k_step(const float* __restrict__ embi, const float* __restrict__ prev,
            const float* __restrict__ Whi, float* __restrict__ cur,
            float* __restrict__ hid, const int sig) {
    const int b = blockIdx.x, cc = blockIdx.y;
    __shared__ float pr[En];
    __shared__ float part[2][128];
    pr[threadIdx.x]       = prev[(size_t)b * En + threadIdx.x];
    pr[threadIdx.x + 256] = prev[(size_t)b * En + threadIdx.x + 256];
    __syncthreads();
    const int col = cc * 128 + (threadIdx.x & 127);
    const int kh  = threadIdx.x >> 7;
    float s = 0.f;
    const float* Wp = Whi + (size_t)(kh * 256) * En + col;
#pragma unroll 8
    for (int k = 0; k < 256; ++k) s += pr[kh * 256 + k] * Wp[(size_t)k * En];
    part[kh][threadIdx.x & 127] = s;
    __syncthreads();
    if (threadIdx.x < 128) {
        float a = part[0][threadIdx.x] + part[1][threadIdx.x] +
                  embi[(size_t)b * En + col];
        if (sig) a = 1.0f / (1.0f + expf(-a));
        else     a = fmaxf(a, 0.f);
        cur[(size_t)b * En + col] = a;
        hid[(size_t)b * En + col] = a;
    }
}

// ---------------------------------------------------------------------------
// K5: preds = curr3 @ Wfinal   [128,512]@[512,5000]
// ---------------------------------------------------------------------------
__global__ __launch_bounds__(256, 2)
void k_preds(const float* __restrict__ cur, const float* __restrict__ Wf,
             float* __restrict__ preds) {
    __shared__ float cs[32 * En];
    const int nt = blockIdx.x;
    const int bt = blockIdx.y;
    for (int idx = threadIdx.x; idx < 32 * 128; idx += 256) {
        const int row = idx >> 7;
        const int c4  = (idx & 127) << 2;
        *(float4*)(cs + row * En + c4) =
            *(const float4*)(cur + (size_t)(bt * 32 + row) * En + c4);
    }
    __syncthreads();
    const int lane = threadIdx.x & 63;
    const int rgrp = threadIdx.x >> 6;
    const int col = nt * 64 + lane;
    float acc[8];
#pragma unroll
    for (int j = 0; j < 8; ++j) acc[j] = 0.f;
    const bool ok = (col < OUTn);
    for (int k = 0; k < En; k += 4) {
        float w0 = 0.f, w1 = 0.f, w2 = 0.f, w3 = 0.f;
        if (ok) {
            w0 = Wf[(size_t)(k + 0) * OUTn + col];
            w1 = Wf[(size_t)(k + 1) * OUTn + col];
            w2 = Wf[(size_t)(k + 2) * OUTn + col];
            w3 = Wf[(size_t)(k + 3) * OUTn + col];
        }
#pragma unroll
        for (int j = 0; j < 8; ++j) {
            const float4 cv = *(const float4*)(cs + (rgrp * 8 + j) * En + k);
            acc[j] += cv.x * w0 + cv.y * w1 + cv.z * w2 + cv.w * w3;
        }
    }
    if (ok) {
#pragma unroll
        for (int j = 0; j < 8; ++j)
            preds[(size_t)(bt * 32 + rgrp * 8 + j) * OUTn + col] = acc[j];
    }
}

// ---------------------------------------------------------------------------
extern "C" void kernel_launch(void* const* d_in, const int* in_sizes, int n_in,
                              void* d_out, int out_size, void* d_ws, size_t ws_size,
                              hipStream_t stream) {
    const int*   sga     = (const int*)d_in[0];
    const int*   can     = (const int*)d_in[1];
    const float* T       = (const float*)d_in[2];
    const float* Wk      = (const float*)d_in[3];
    const float* bk      = (const float*)d_in[4];
    const float* Wq      = (const float*)d_in[5];
    // d_in[6] = bq: unused — constant over softmax axis, cancels exactly
    const float* can_emb = (const float*)d_in[7];
    const float* Wh      = (const float*)d_in[8];
    const float* Wf      = (const float*)d_in[9];

    float* out = (float*)d_out;
    float* ws  = (float*)d_ws;

    // workspace layout in float slots (all 16B-aligned; embw & cnt contiguous)
    size_t o = 0;
    auto alloc = [&](size_t n) { size_t r = o; o += (n + 3) & ~(size_t)3; return r; };
    float* scoresv = ws + alloc(608032);                 // NB*V1*NH
    float* embw    = ws + alloc((size_t)NBn * Bn * En);  // 262144
    int*   cnt     = (int*)(ws + alloc(NBIN));           // 38016 (follows embw)
    int*   offs    = (int*)(ws + alloc(NBIN + 1));
    int*   cursor  = (int*)(ws + alloc(NBIN));
    int2*  payload = (int2*)(ws + alloc(2 * (size_t)Bn * In));
    float* cur0    = ws + alloc((size_t)Bn * En);
    float* cur1    = ws + alloc((size_t)Bn * En);
    ushort* Wkt    = (ushort*)(ws + alloc((size_t)NBn * En * En / 2));
    ushort* Tbf    = (ushort*)(ws + alloc((size_t)NBn * V1 * En / 2));
    const bool useTbf = (ws_size >= o * 4);

    float* preds_out = out;
    float* attn_out  = out + OFF_ATTN;
    float* hid_out   = out + OFF_HID;

    // K0: Wk -> bf16 transposed [nb][n][k]
    k_prep<<<dim3(8, 8, NBn), 256, 0, stream>>>(Wk, Wkt);

    if (useTbf) {
        // zero embw + cnt (contiguous)
        const int nz = NBn * Bn * En + NBIN;
        k_zero<<<(nz + 255) / 256, 256, 0, stream>>>(embw, nz);
        // inverted index over sga
        k_hist<<<(Bn * In + 255) / 256, 256, 0, stream>>>(sga, cnt);
        k_scan<<<1, 256, 0, stream>>>(cnt, offs, cursor);
        k_fill<<<(Bn * In + 255) / 256, 256, 0, stream>>>(sga, cursor, payload);
        // K1 (+Tbf side-store)
        k_scores<true><<<dim3((V1 + 31) / 32, NBn), 256, 0, stream>>>(
            T, Wkt, bk, Wq, scoresv, Tbf);
        k_softmax<<<dim3(Bn, NBn), 256, 0, stream>>>(sga, scoresv, attn_out);
        k_emb2<<<dim3(32, 4, NBn), 256, 0, stream>>>(payload, offs, attn_out,
                                                     Tbf, embw);
    } else {
        k_scores<false><<<dim3((V1 + 31) / 32, NBn), 256, 0, stream>>>(
            T, Wkt, bk, Wq, scoresv, Tbf);
        k_softmax<<<dim3(Bn, NBn), 256, 0, stream>>>(sga, scoresv, attn_out);
        k_embf<<<dim3(Bn, NBn), 512, 0, stream>>>(sga, attn_out, T, embw);
    }

    // K4: residual chain
    k_step0<<<Bn, 256, 0, stream>>>(embw, can, can_emb, cur0, hid_out);
    k_step<<<dim3(Bn, 4), 256, 0, stream>>>(embw + 1 * Bn * En, cur0,
                                            Wh + 0 * En * En, cur1,
                                            hid_out + 1 * (size_t)Bn * En, 0);
    k_step<<<dim3(Bn, 4), 256, 0, stream>>>(embw + 2 * Bn * En, cur1,
                                            Wh + 1 * En * En, cur0,
                                            hid_out + 2 * (size_t)Bn * En, 0);
    k_step<<<dim3(Bn, 4), 256, 0, stream>>>(embw + 3 * Bn * En, cur0,
                                            Wh + 2 * En * En, cur1,
                                            hid_out + 3 * (size_t)Bn * En, 1);
    // K5: final projection
    k_preds<<<dim3((OUTn + 63) / 64, Bn / 32), 256, 0, stream>>>(cur1, Wf, preds_out);
}

// Round 6
// 702.873 us; speedup vs baseline: 1.4738x; 1.4738x over previous
//
#include <hip/hip_runtime.h>
#include <hip/hip_bf16.h>

// Problem constants
constexpr int Bn   = 128;    // batch
constexpr int In   = 800;    // genes per case
constexpr int En   = 512;    // embed dim
constexpr int V1   = 19001;  // vocab + padding row
constexpr int NHn  = 8;      // heads
constexpr int NBn  = 4;      // attention blocks
constexpr int OUTn = 5000;   // output genes

constexpr int MPAD = 19072;  // V1 padded to 149*128 (k_scores m-tiles)
constexpr int KPAD = 19456;  // V1 padded to 16*38*32 (emb-GEMM K-split)
constexpr int KSn  = 16;     // emb-GEMM K-split factor (1216 = 38*32 each)

// d_out layout (floats): preds [B,OUT] | attns [NB,B,I] | hiddens [NB,B,E]
constexpr int OFF_ATTN = Bn * OUTn;                 // 640000
constexpr int OFF_HID  = OFF_ATTN + NBn * Bn * In;  // 1049600

typedef __attribute__((ext_vector_type(8))) short bf16x8;
typedef __attribute__((ext_vector_type(8))) unsigned short u16x8;
typedef __attribute__((ext_vector_type(4))) float f32x4;

__device__ inline ushort f2bf(float x) {
    __hip_bfloat16 h = __float2bfloat16(x);
    return *reinterpret_cast<ushort*>(&h);
}
__device__ inline void gl_lds16(const ushort* g, ushort* l) {
    __builtin_amdgcn_global_load_lds(
        (const __attribute__((address_space(1))) void*)g,
        (__attribute__((address_space(3))) void*)l, 16, 0, 0);
}

// ---------------------------------------------------------------------------
// K0: Wkt[nb][n][k] = bf16(Wk[nb][k][n]) via LDS tile transpose
// ---------------------------------------------------------------------------
__global__ __launch_bounds__(256)
void k_prep(const float* __restrict__ Wk, ushort* __restrict__ Wkt) {
    __shared__ float ts[64][65];
    const int n0 = blockIdx.x * 64, k0 = blockIdx.y * 64, nb = blockIdx.z;
    const int t = threadIdx.x;
    {
        const int kr = t >> 2, nc = (t & 3) * 16;
        const float* p = Wk + (((size_t)nb * En) + (k0 + kr)) * En + n0 + nc;
#pragma unroll
        for (int j = 0; j < 4; ++j) {
            const float4 v = *(const float4*)(p + j * 4);
            ts[kr][nc + j * 4 + 0] = v.x; ts[kr][nc + j * 4 + 1] = v.y;
            ts[kr][nc + j * 4 + 2] = v.z; ts[kr][nc + j * 4 + 3] = v.w;
        }
    }
    __syncthreads();
    {
        const int nr = t >> 2, kc = (t & 3) * 16;
        ushort* d = Wkt + (((size_t)nb * En) + (n0 + nr)) * En + k0 + kc;
        ushort4 o;
#pragma unroll
        for (int j = 0; j < 4; ++j) {
            o.x = f2bf(ts[kc + j * 4 + 0][nr]); o.y = f2bf(ts[kc + j * 4 + 1][nr]);
            o.z = f2bf(ts[kc + j * 4 + 2][nr]); o.w = f2bf(ts[kc + j * 4 + 3][nr]);
            *(ushort4*)(d + j * 4) = o;
        }
    }
}

// ---------------------------------------------------------------------------
// K0b: TbfT[nb][e][v] = bf16(T[nb][v][e])  (transpose+convert; pad v -> 0)
// grid (298 v-tiles, 8 e-tiles, nb); 64x64 tiles
// ---------------------------------------------------------------------------
__global__ __launch_bounds__(256)
void k_cvt(const float* __restrict__ T, ushort* __restrict__ TbfT) {
    __shared__ float ts[64][65];
    const int v0 = blockIdx.x * 64, e0 = blockIdx.y * 64, nb = blockIdx.z;
    const int t = threadIdx.x;
    {
        const int vr = t >> 2, ec = (t & 3) * 16;
        const int v = v0 + vr;
        float4 f[4];
        if (v < V1) {
            const float* p = T + (((size_t)nb * V1) + v) * En + e0 + ec;
#pragma unroll
            for (int j = 0; j < 4; ++j) f[j] = *(const float4*)(p + j * 4);
        } else {
#pragma unroll
            for (int j = 0; j < 4; ++j) f[j] = make_float4(0.f, 0.f, 0.f, 0.f);
        }
#pragma unroll
        for (int j = 0; j < 4; ++j) {
            ts[vr][ec + j * 4 + 0] = f[j].x; ts[vr][ec + j * 4 + 1] = f[j].y;
            ts[vr][ec + j * 4 + 2] = f[j].z; ts[vr][ec + j * 4 + 3] = f[j].w;
        }
    }
    __syncthreads();
    {
        const int er = t >> 2, vc = (t & 3) * 16;
        ushort* d = TbfT + (((size_t)nb * En) + (e0 + er)) * KPAD + v0 + vc;
        ushort4 o;
#pragma unroll
        for (int j = 0; j < 4; ++j) {
            o.x = f2bf(ts[vc + j * 4 + 0][er]); o.y = f2bf(ts[vc + j * 4 + 1][er]);
            o.z = f2bf(ts[vc + j * 4 + 2][er]); o.w = f2bf(ts[vc + j * 4 + 3][er]);
            *(ushort4*)(d + j * 4) = o;
        }
    }
}

// ---------------------------------------------------------------------------
__global__ __launch_bounds__(256)
void k_zero(float* __restrict__ p, int n) {
    const int i = blockIdx.x * 256 + threadIdx.x;
    if (i < n) p[i] = 0.f;
}

// ---------------------------------------------------------------------------
// K1: scoresv[nb][v][h]; keys = tanh(T@Wk+bk), scores = keys@Wq (bq cancels).
// m97 structure: 128x128 C-tile, BK=32, 16 iters, single-buffer 2-barrier
// K-loop. B (Wkt [n][k] bf16) via global_load_lds; A (T fp32) manual
// stage+convert. 16 KB LDS. 4 waves 2x2, wave tile 64x64 (acc[4][4]).
// Epilogue: tanh + per-head VALU dots + 16-lane butterfly + LDS cross-wave
// reduce (overlaying staging LDS) -> direct stores.
// ---------------------------------------------------------------------------
__global__ __launch_bounds__(256, 3)
void k_scores(const float* __restrict__ T, const ushort* __restrict__ Wkt,
              const float* __restrict__ bk, const float* __restrict__ Wq,
              float* __restrict__ scoresv) {
    __shared__ union {
        struct { ushort A[128][32]; ushort B[128][32]; } s;  // 16 KB
        float red[2][128][NHn];                              // 8 KB
    } u;
    const int mblk = blockIdx.x, nblk = blockIdx.y, nb = blockIdx.z;
    const int v0 = mblk * 128;
    const int tid = threadIdx.x, lane = tid & 63, wv = tid >> 6;
    const int wm = wv & 1, wn = wv >> 1;
    const int q = lane >> 4, c = lane & 15;

    const float*  Tb = T + (size_t)nb * V1 * En;
    const ushort* Wn = Wkt + (size_t)nb * En * En;

    // A staging map: thread t -> row t>>1, 16-float half t&1
    const int arow = tid >> 1, ah = tid & 1;
    const int vra = v0 + arow;
    const float* agp = Tb + (size_t)vra * En + ah * 16;
    const bool aok = vra < V1;

    f32x4 acc[4][4];
#pragma unroll
    for (int mt = 0; mt < 4; ++mt)
#pragma unroll
        for (int nt = 0; nt < 4; ++nt) acc[mt][nt] = (f32x4)0.0f;

    for (int it = 0; it < 16; ++it) {
        const int k0 = it * 32;
        // --- stage B via glds: 2 insts/wave, rows (wv*2+j)*16 .. +16 ---
#pragma unroll
        for (int j = 0; j < 2; ++j) {
            const int nr = (wv * 2 + j) * 16;
            const ushort* gp = Wn + (size_t)(nblk * 128 + nr + (lane >> 2)) * En +
                               k0 + (lane & 3) * 8;
            gl_lds16(gp, &u.s.B[nr][0]);
        }
        // --- stage A: fp32 -> bf16 manual ---
        {
            float4 f0 = make_float4(0, 0, 0, 0), f1 = f0, f2 = f0, f3 = f0;
            if (aok) {
                f0 = *(const float4*)(agp + k0);
                f1 = *(const float4*)(agp + k0 + 4);
                f2 = *(const float4*)(agp + k0 + 8);
                f3 = *(const float4*)(agp + k0 + 12);
            }
            u16x8 o0, o1;
            o0[0] = f2bf(f0.x); o0[1] = f2bf(f0.y); o0[2] = f2bf(f0.z); o0[3] = f2bf(f0.w);
            o0[4] = f2bf(f1.x); o0[5] = f2bf(f1.y); o0[6] = f2bf(f1.z); o0[7] = f2bf(f1.w);
            o1[0] = f2bf(f2.x); o1[1] = f2bf(f2.y); o1[2] = f2bf(f2.z); o1[3] = f2bf(f2.w);
            o1[4] = f2bf(f3.x); o1[5] = f2bf(f3.y); o1[6] = f2bf(f3.z); o1[7] = f2bf(f3.w);
            *(u16x8*)&u.s.A[arow][ah * 16]     = o0;
            *(u16x8*)&u.s.A[arow][ah * 16 + 8] = o1;
        }
        __syncthreads();
        bf16x8 aF[4], bF[4];
#pragma unroll
        for (int mt = 0; mt < 4; ++mt)
            aF[mt] = *(bf16x8*)&u.s.A[wm * 64 + mt * 16 + c][q * 8];
#pragma unroll
        for (int nt = 0; nt < 4; ++nt)
            bF[nt] = *(bf16x8*)&u.s.B[wn * 64 + nt * 16 + c][q * 8];
#pragma unroll
        for (int nt = 0; nt < 4; ++nt)
#pragma unroll
            for (int mt = 0; mt < 4; ++mt)
                acc[mt][nt] = __builtin_amdgcn_mfma_f32_16x16x32_bf16(
                    aF[mt], bF[nt], acc[mt][nt], 0, 0, 0);
        __syncthreads();
    }

    // --- keys = tanh(acc + bk[col]) ---
#pragma unroll
    for (int nt = 0; nt < 4; ++nt) {
        const float bb = bk[nb * En + nblk * 128 + wn * 64 + nt * 16 + c];
#pragma unroll
        for (int mt = 0; mt < 4; ++mt)
#pragma unroll
            for (int r = 0; r < 4; ++r)
                acc[mt][nt][r] = tanhf(acc[mt][nt][r] + bb);
    }

    // --- per-head dots over this wave's 64 cols + butterfly over c ---
    for (int h = 0; h < NHn; ++h) {
        float wqh[4];
#pragma unroll
        for (int nt = 0; nt < 4; ++nt)
            wqh[nt] =
                Wq[((size_t)nb * En + nblk * 128 + wn * 64 + nt * 16 + c) * NHn + h];
        float p[4][4];
#pragma unroll
        for (int mt = 0; mt < 4; ++mt)
#pragma unroll
            for (int r = 0; r < 4; ++r) {
                float s = 0.f;
#pragma unroll
                for (int nt = 0; nt < 4; ++nt) s += acc[mt][nt][r] * wqh[nt];
                p[mt][r] = s;
            }
#pragma unroll
        for (int m = 1; m < 16; m <<= 1) {
#pragma unroll
            for (int mt = 0; mt < 4; ++mt)
#pragma unroll
                for (int r = 0; r < 4; ++r) p[mt][r] += __shfl_xor(p[mt][r], m, 64);
        }
        if (c == h) {
#pragma unroll
            for (int mt = 0; mt < 4; ++mt)
#pragma unroll
                for (int r = 0; r < 4; ++r)
                    u.red[wn][wm * 64 + mt * 16 + q * 4 + r][h] = p[mt][r];
        }
    }
    __syncthreads();
    for (int idx = tid; idx < 128 * NHn; idx += 256) {
        const int row = idx >> 3, h = idx & 7;
        const int vr = v0 + row;
        if (vr < V1)
            scoresv[((size_t)nb * V1 + vr) * NHn + h] =
                u.red[0][row][h] + u.red[1][row][h];
    }
}

// ---------------------------------------------------------------------------
// K2: masked softmax over genes, per (nb, b); writes attn weights (head-sum).
// ---------------------------------------------------------------------------
__global__ __launch_bounds__(256)
void k_softmax(const int* __restrict__ sga, const float* __restrict__ scoresv,
               float* __restrict__ attn_out) {
    const int b  = blockIdx.x;
    const int nb = blockIdx.y;
    const int tid = threadIdx.x;
    const int lane = tid & 63;
    const int wid  = tid >> 6;
    __shared__ float red[4 * NHn];

    float sc[4][NHn];
    int ivals[4];
#pragma unroll
    for (int s = 0; s < 4; ++s) {
        const int i = tid + s * 256;
        ivals[s] = i;
        if (i < In) {
            const int v = sga[b * In + i];
            const float4 s0 = *(const float4*)(scoresv + ((size_t)nb * V1 + v) * NHn);
            const float4 s1 = *(const float4*)(scoresv + ((size_t)nb * V1 + v) * NHn + 4);
            sc[s][0] = s0.x; sc[s][1] = s0.y; sc[s][2] = s0.z; sc[s][3] = s0.w;
            sc[s][4] = s1.x; sc[s][5] = s1.y; sc[s][6] = s1.z; sc[s][7] = s1.w;
            if (v == 0) {
#pragma unroll
                for (int n = 0; n < NHn; ++n) sc[s][n] = -1e9f;
            }
        } else {
#pragma unroll
            for (int n = 0; n < NHn; ++n) sc[s][n] = -3.0e38f;
        }
    }

    float lm[NHn];
#pragma unroll
    for (int n = 0; n < NHn; ++n)
        lm[n] = fmaxf(fmaxf(sc[0][n], sc[1][n]), fmaxf(sc[2][n], sc[3][n]));
#pragma unroll
    for (int m = 1; m < 64; m <<= 1) {
#pragma unroll
        for (int n = 0; n < NHn; ++n) lm[n] = fmaxf(lm[n], __shfl_xor(lm[n], m, 64));
    }
    if (lane == 0) {
#pragma unroll
        for (int n = 0; n < NHn; ++n) red[wid * NHn + n] = lm[n];
    }
    __syncthreads();
    float M[NHn];
#pragma unroll
    for (int n = 0; n < NHn; ++n)
        M[n] = fmaxf(fmaxf(red[n], red[NHn + n]), fmaxf(red[2 * NHn + n], red[3 * NHn + n]));
    __syncthreads();

    float ls[NHn];
#pragma unroll
    for (int n = 0; n < NHn; ++n) ls[n] = 0.f;
#pragma unroll
    for (int s = 0; s < 4; ++s) {
#pragma unroll
        for (int n = 0; n < NHn; ++n) {
            sc[s][n] = expf(sc[s][n] - M[n]);
            ls[n] += sc[s][n];
        }
    }
#pragma unroll
    for (int m = 1; m < 64; m <<= 1) {
#pragma unroll
        for (int n = 0; n < NHn; ++n) ls[n] += __shfl_xor(ls[n], m, 64);
    }
    if (lane == 0) {
#pragma unroll
        for (int n = 0; n < NHn; ++n) red[wid * NHn + n] = ls[n];
    }
    __syncthreads();
    float inv[NHn];
#pragma unroll
    for (int n = 0; n < NHn; ++n) {
        const float S = red[n] + red[NHn + n] + red[2 * NHn + n] + red[3 * NHn + n];
        inv[n] = 1.0f / S;
    }

#pragma unroll
    for (int s = 0; s < 4; ++s) {
        if (ivals[s] < In) {
            float w = 0.f;
#pragma unroll
            for (int n = 0; n < NHn; ++n) w += sc[s][n] * inv[n];
            attn_out[((size_t)nb * Bn + b) * In + ivals[s]] = w;
        }
    }
}

// ---------------------------------------------------------------------------
// K3a: scatter attn weights into dense W[nb][b][KPAD] (atomicAdd, dups add)
// ---------------------------------------------------------------------------
__global__ __launch_bounds__(256)
void k_wfill(const int* __restrict__ sga, const float* __restrict__ attn,
             float* __restrict__ Wd) {
    const int idx = blockIdx.x * 256 + threadIdx.x;
    if (idx >= Bn * In) return;
    const int b = idx / In, i = idx - b * In;
    const int v = sga[idx];
#pragma unroll
    for (int nb = 0; nb < NBn; ++nb)
        atomicAdd(Wd + ((size_t)nb * Bn + b) * KPAD + v,
                  attn[((size_t)nb * Bn + b) * In + i]);
}

// ---------------------------------------------------------------------------
// K3b: partial[ks][nb][b][e] = W[nb][b][kchunk] @ TbfT[nb][e][kchunk]^T
// Same MFMA structure as k_scores: M=128 (b), N=128 (e-tile), 38 K-iters.
// grid (4 e-tiles, 16 ks, nb)
// ---------------------------------------------------------------------------
__global__ __launch_bounds__(256, 3)
void k_emb_gemm(const float* __restrict__ Wd, const ushort* __restrict__ TbfT,
                float* __restrict__ partial) {
    __shared__ struct { ushort A[128][32]; ushort B[128][32]; } s;  // 16 KB
    const int eblk = blockIdx.x, ks = blockIdx.y, nb = blockIdx.z;
    const int tid = threadIdx.x, lane = tid & 63, wv = tid >> 6;
    const int wm = wv & 1, wn = wv >> 1;
    const int q = lane >> 4, c = lane & 15;

    const float*  Wb = Wd + (size_t)nb * Bn * KPAD;
    const ushort* Tt = TbfT + (size_t)nb * En * KPAD;

    const int arow = tid >> 1, ah = tid & 1;  // b-row, 16-float half
    const float* agp = Wb + (size_t)arow * KPAD + ah * 16;

    f32x4 acc[4][4];
#pragma unroll
    for (int mt = 0; mt < 4; ++mt)
#pragma unroll
        for (int nt = 0; nt < 4; ++nt) acc[mt][nt] = (f32x4)0.0f;

    const int kbase = ks * 1216;
    for (int it = 0; it < 38; ++it) {
        const int k0 = kbase + it * 32;
#pragma unroll
        for (int j = 0; j < 2; ++j) {
            const int nr = (wv * 2 + j) * 16;
            const ushort* gp = Tt + (size_t)(eblk * 128 + nr + (lane >> 2)) * KPAD +
                               k0 + (lane & 3) * 8;
            gl_lds16(gp, &s.B[nr][0]);
        }
        {
            const float4 f0 = *(const float4*)(agp + k0);
            const float4 f1 = *(const float4*)(agp + k0 + 4);
            const float4 f2 = *(const float4*)(agp + k0 + 8);
            const float4 f3 = *(const float4*)(agp + k0 + 12);
            u16x8 o0, o1;
            o0[0] = f2bf(f0.x); o0[1] = f2bf(f0.y); o0[2] = f2bf(f0.z); o0[3] = f2bf(f0.w);
            o0[4] = f2bf(f1.x); o0[5] = f2bf(f1.y); o0[6] = f2bf(f1.z); o0[7] = f2bf(f1.w);
            o1[0] = f2bf(f2.x); o1[1] = f2bf(f2.y); o1[2] = f2bf(f2.z); o1[3] = f2bf(f2.w);
            o1[4] = f2bf(f3.x); o1[5] = f2bf(f3.y); o1[6] = f2bf(f3.z); o1[7] = f2bf(f3.w);
            *(u16x8*)&s.A[arow][ah * 16]     = o0;
            *(u16x8*)&s.A[arow][ah * 16 + 8] = o1;
        }
        __syncthreads();
        bf16x8 aF[4], bF[4];
#pragma unroll
        for (int mt = 0; mt < 4; ++mt)
            aF[mt] = *(bf16x8*)&s.A[wm * 64 + mt * 16 + c][q * 8];
#pragma unroll
        for (int nt = 0; nt < 4; ++nt)
            bF[nt] = *(bf16x8*)&s.B[wn * 64 + nt * 16 + c][q * 8];
#pragma unroll
        for (int nt = 0; nt < 4; ++nt)
#pragma unroll
            for (int mt = 0; mt < 4; ++mt)
                acc[mt][nt] = __builtin_amdgcn_mfma_f32_16x16x32_bf16(
                    aF[mt], bF[nt], acc[mt][nt], 0, 0, 0);
        __syncthreads();
    }

    float* dst = partial + ((size_t)ks * NBn + nb) * (Bn * En);
#pragma unroll
    for (int mt = 0; mt < 4; ++mt)
#pragma unroll
        for (int nt = 0; nt < 4; ++nt) {
            const int e = eblk * 128 + wn * 64 + nt * 16 + c;
#pragma unroll
            for (int r = 0; r < 4; ++r) {
                const int b = wm * 64 + mt * 16 + q * 4 + r;
                dst[(size_t)b * En + e] = acc[mt][nt][r];
            }
        }
}

// ---------------------------------------------------------------------------
// K3c: embw[i] = sum_ks partial[ks][i]   (i over NB*B*E)
// ---------------------------------------------------------------------------
__global__ __launch_bounds__(256)
void k_emb_red(const float* __restrict__ partial, float* __restrict__ embw) {
    const int i = blockIdx.x * 256 + threadIdx.x;
    if (i >= NBn * Bn * En) return;
    float s = 0.f;
#pragma unroll
    for (int ks = 0; ks < KSn; ++ks)
        s += partial[(size_t)ks * (NBn * Bn * En) + i];
    embw[i] = s;
}

// ---------------------------------------------------------------------------
// K3 (fallback): direct fp32 gather
// ---------------------------------------------------------------------------
__global__ __launch_bounds__(512)
void k_embf(const int* __restrict__ sga, const float* __restrict__ attn,
            const float* __restrict__ T, float* __restrict__ emb) {
    const int b  = blockIdx.x;
    const int nb = blockIdx.y;
    __shared__ int   sv[In];
    __shared__ float sw[In];
    __shared__ float pa[8][En];
    for (int idx = threadIdx.x; idx < In; idx += 512) {
        sv[idx] = sga[b * In + idx];
        sw[idx] = attn[((size_t)nb * Bn + b) * In + idx];
    }
    __syncthreads();
    const int wave = threadIdx.x >> 6, lane = threadIdx.x & 63;
    float a[8];
#pragma unroll
    for (int j = 0; j < 8; ++j) a[j] = 0.f;
    const float* Tb = T + (size_t)nb * V1 * En;
#pragma unroll 4
    for (int g = 0; g < 100; ++g) {
        const int i = wave * 100 + g;
        const int v = sv[i];
        const float w = sw[i];
        const float4* p = (const float4*)(Tb + (size_t)v * En) + lane * 2;
        const float4 t0 = p[0], t1 = p[1];
        a[0] += w * t0.x; a[1] += w * t0.y; a[2] += w * t0.z; a[3] += w * t0.w;
        a[4] += w * t1.x; a[5] += w * t1.y; a[6] += w * t1.z; a[7] += w * t1.w;
    }
#pragma unroll
    for (int j = 0; j < 8; ++j) pa[wave][lane * 8 + j] = a[j];
    __syncthreads();
    const int t = threadIdx.x;
    float s = 0.f;
#pragma unroll
    for (int wv = 0; wv < 8; ++wv) s += pa[wv][t];
    emb[((size_t)nb * Bn + b) * En + t] = s;
}

// ---------------------------------------------------------------------------
// K4a: curr0 = relu(emb0 + can_emb[can]); hiddens[0] = curr0
// ---------------------------------------------------------------------------
__global__ __launch_bounds__(256)
void k_step0(const float* __restrict__ emb0, const int* __restrict__ can,
             const float* __restrict__ can_emb, float* __restrict__ cur,
             float* __restrict__ hid) {
    const int b = blockIdx.x;
    const int e0 = threadIdx.x * 2;
    const int c = can[b];
    float2 v = *(const float2*)(emb0 + (size_t)b * En + e0);
    const float2 ce = *(const float2*)(can_emb + (size_t)c * En + e0);
    v.x = fmaxf(v.x + ce.x, 0.f);
    v.y = fmaxf(v.y + ce.y, 0.f);
    *(float2*)(cur + (size_t)b * En + e0) = v;
    *(float2*)(hid + (size_t)b * En + e0) = v;
}

// ---------------------------------------------------------------------------
// K4b: curr = act(emb_i + prev @ Wh), K-split, grid (b, 4 col-chunks)
// ---------------------------------------------------------------------------
__global__ __launch_bounds__(256)
void k_step(const float* __restrict__ embi, const float* __restrict__ prev,
            const float* __restrict__ Whi, float* __restrict__ cur,
            float* __restrict__ hid, const int sig) {
    const int b = blockIdx.x, cc = blockIdx.y;
    __shared__ float pr[En];
    __shared__ float part[2][128];
    pr[threadIdx.x]       = prev[(size_t)b * En + threadIdx.x];
    pr[threadIdx.x + 256] = prev[(size_t)b * En + threadIdx.x + 256];
    __syncthreads();
    const int col = cc * 128 + (threadIdx.x & 127);
    const int kh  = threadIdx.x >> 7;
    float s = 0.f;
    const float* Wp = Whi + (size_t)(kh * 256) * En + col;
#pragma unroll 8
    for (int k = 0; k < 256; ++k) s += pr[kh * 256 + k] * Wp[(size_t)k * En];
    part[kh][threadIdx.x & 127] = s;
    __syncthreads();
    if (threadIdx.x < 128) {
        float a = part[0][threadIdx.x] + part[1][threadIdx.x] +
                  embi[(size_t)b * En + col];
        if (sig) a = 1.0f / (1.0f + expf(-a));
        else     a = fmaxf(a, 0.f);
        cur[(size_t)b * En + col] = a;
        hid[(size_t)b * En + col] = a;
    }
}

// ---------------------------------------------------------------------------
// K5: preds = curr3 @ Wfinal   [128,512]@[512,5000]
// ---------------------------------------------------------------------------
__global__ __launch_bounds__(256, 2)
void k_preds(const float* __restrict__ cur, const float* __restrict__ Wf,
             float* __restrict__ preds) {
    __shared__ float cs[32 * En];
    const int nt = blockIdx.x;
    const int bt = blockIdx.y;
    for (int idx = threadIdx.x; idx < 32 * 128; idx += 256) {
        const int row = idx >> 7;
        const int c4  = (idx & 127) << 2;
        *(float4*)(cs + row * En + c4) =
            *(const float4*)(cur + (size_t)(bt * 32 + row) * En + c4);
    }
    __syncthreads();
    const int lane = threadIdx.x & 63;
    const int rgrp = threadIdx.x >> 6;
    const int col = nt * 64 + lane;
    float acc[8];
#pragma unroll
    for (int j = 0; j < 8; ++j) acc[j] = 0.f;
    const bool ok = (col < OUTn);
    for (int k = 0; k < En; k += 4) {
        float w0 = 0.f, w1 = 0.f, w2 = 0.f, w3 = 0.f;
        if (ok) {
            w0 = Wf[(size_t)(k + 0) * OUTn + col];
            w1 = Wf[(size_t)(k + 1) * OUTn + col];
            w2 = Wf[(size_t)(k + 2) * OUTn + col];
            w3 = Wf[(size_t)(k + 3) * OUTn + col];
        }
#pragma unroll
        for (int j = 0; j < 8; ++j) {
            const float4 cv = *(const float4*)(cs + (rgrp * 8 + j) * En + k);
            acc[j] += cv.x * w0 + cv.y * w1 + cv.z * w2 + cv.w * w3;
        }
    }
    if (ok) {
#pragma unroll
        for (int j = 0; j < 8; ++j)
            preds[(size_t)(bt * 32 + rgrp * 8 + j) * OUTn + col] = acc[j];
    }
}

// ---------------------------------------------------------------------------
extern "C" void kernel_launch(void* const* d_in, const int* in_sizes, int n_in,
                              void* d_out, int out_size, void* d_ws, size_t ws_size,
                              hipStream_t stream) {
    const int*   sga     = (const int*)d_in[0];
    const int*   can     = (const int*)d_in[1];
    const float* T       = (const float*)d_in[2];
    const float* Wk      = (const float*)d_in[3];
    const float* bk      = (const float*)d_in[4];
    const float* Wq      = (const float*)d_in[5];
    // d_in[6] = bq: unused — constant over softmax axis, cancels exactly
    const float* can_emb = (const float*)d_in[7];
    const float* Wh      = (const float*)d_in[8];
    const float* Wf      = (const float*)d_in[9];

    float* out = (float*)d_out;
    float* ws  = (float*)d_ws;

    // workspace layout in float slots (small prefix first, big arrays last)
    size_t o = 0;
    auto alloc = [&](size_t n) { size_t r = o; o += (n + 3) & ~(size_t)3; return r; };
    float* scoresv = ws + alloc((size_t)NBn * V1 * NHn);   // 2.43 MB
    float* embw    = ws + alloc((size_t)NBn * Bn * En);    // 1 MB
    float* cur0    = ws + alloc((size_t)Bn * En);
    float* cur1    = ws + alloc((size_t)Bn * En);
    ushort* Wkt    = (ushort*)(ws + alloc((size_t)NBn * En * En / 2));  // 2 MB
    const size_t small_need = o * 4;
    float* Wd      = ws + alloc((size_t)NBn * Bn * KPAD);          // 39.8 MB
    float* partial = ws + alloc((size_t)KSn * NBn * Bn * En);      // 16.8 MB
    ushort* TbfT   = (ushort*)(ws + alloc((size_t)NBn * En * KPAD / 2));  // 79.7 MB
    const bool fast = (ws_size >= o * 4);
    (void)small_need;

    float* preds_out = out;
    float* attn_out  = out + OFF_ATTN;
    float* hid_out   = out + OFF_HID;

    // K0: Wk -> bf16 transposed [nb][n][k]
    k_prep<<<dim3(8, 8, NBn), 256, 0, stream>>>(Wk, Wkt);
    // K1: fused keys-GEMM + scores epilogue
    k_scores<<<dim3(MPAD / 128, 4, NBn), 256, 0, stream>>>(T, Wkt, bk, Wq, scoresv);
    // K2: softmax + head-sum -> attns (directly to d_out)
    k_softmax<<<dim3(Bn, NBn), 256, 0, stream>>>(sga, scoresv, attn_out);

    if (fast) {
        // T -> TbfT bf16 transposed (independent; any order)
        k_cvt<<<dim3(MPAD / 64, En / 64, NBn), 256, 0, stream>>>(T, TbfT);
        // dense weight matrix: zero + scatter
        const int nwd = NBn * Bn * KPAD;
        k_zero<<<(nwd + 255) / 256, 256, 0, stream>>>(Wd, nwd);
        k_wfill<<<(Bn * In + 255) / 256, 256, 0, stream>>>(sga, attn_out, Wd);
        // emb = Wd @ TbfT^T  (K-split) + reduce
        k_emb_gemm<<<dim3(En / 128, KSn, NBn), 256, 0, stream>>>(Wd, TbfT, partial);
        const int ne = NBn * Bn * En;
        k_emb_red<<<(ne + 255) / 256, 256, 0, stream>>>(partial, embw);
    } else {
        k_embf<<<dim3(Bn, NBn), 512, 0, stream>>>(sga, attn_out, T, embw);
    }

    // K4: residual chain
    k_step0<<<Bn, 256, 0, stream>>>(embw, can, can_emb, cur0, hid_out);
    k_step<<<dim3(Bn, 4), 256, 0, stream>>>(embw + 1 * Bn * En, cur0,
                                            Wh + 0 * En * En, cur1,
                                            hid_out + 1 * (size_t)Bn * En, 0);
    k_step<<<dim3(Bn, 4), 256, 0, stream>>>(embw + 2 * Bn * En, cur1,
                                            Wh + 1 * En * En, cur0,
                                            hid_out + 2 * (size_t)Bn * En, 0);
    k_step<<<dim3(Bn, 4), 256, 0, stream>>>(embw + 3 * Bn * En, cur0,
                                            Wh + 2 * En * En, cur1,
                                            hid_out + 3 * (size_t)Bn * En, 1);
    // K5: final projection
    k_preds<<<dim3((OUTn + 63) / 64, Bn / 32), 256, 0, stream>>>(cur1, Wf, preds_out);
}